// Round 7
// baseline (262.114 us; speedup 1.0000x reference)
//
#include <hip/hip_runtime.h>
#include <hip/hip_fp16.h>

#define N_NODES 50000
#define N_EDGES 800000
#define D_IN 128
#define D_HID 256
#define D_OUT 128
#define NCHUNK 196   // ceil(N_NODES / 256)
#define NTILES 3125  // N_NODES / 16 exact
#define GEMM_GRID 512

typedef _Float16 f16x8 __attribute__((ext_vector_type(8)));
typedef float f32x4 __attribute__((ext_vector_type(4)));

// ---------------- fused prep: zero_deg + cvt x + cvt weights ------------------
// 16B/lane vectorized: blocks [0,3125): xb; [3125,3141): 4 weight mats;
// [3141,3337): zero deg.   (R1-proven exact)

__device__ __forceinline__ void cvt8(const float* __restrict__ src,
                                     __half* __restrict__ dstp, int i) {
    const float4* s4 = (const float4*)src;
    float4 a = s4[i * 2];
    float4 b = s4[i * 2 + 1];
    float4 o;
    __half2* op = (__half2*)&o;
    op[0] = __float22half2_rn(make_float2(a.x, a.y));
    op[1] = __float22half2_rn(make_float2(a.z, a.w));
    op[2] = __float22half2_rn(make_float2(b.x, b.y));
    op[3] = __float22half2_rn(make_float2(b.z, b.w));
    ((float4*)dstp)[i] = o;
}

__global__ __launch_bounds__(256)
void prep_kernel(const float* __restrict__ x, __half* __restrict__ xb,
                 const float* __restrict__ Wl1, const float* __restrict__ Wr1,
                 const float* __restrict__ Wl2, const float* __restrict__ Wr2,
                 __half* __restrict__ wl1h, __half* __restrict__ wr1h,
                 __half* __restrict__ wl2h, __half* __restrict__ wr2h,
                 int* __restrict__ deg) {
    int b = blockIdx.x;
    if (b < 3125) {
        int i = b * 256 + threadIdx.x;            // 800000 threads x 8 floats
        cvt8(x, xb, i);
    } else if (b < 3141) {
        int i = (b - 3125) * 256 + threadIdx.x;   // 4096 threads x 8 floats/mat
        cvt8(Wl1, wl1h, i);
        cvt8(Wr1, wr1h, i);
        cvt8(Wl2, wl2h, i);
        cvt8(Wr2, wr2h, i);
    } else {
        int i = (b - 3141) * 256 + threadIdx.x;
        if (i < N_NODES) deg[i] = 0;
    }
}

// ---------------- CSR build: rank-split (atomic pass separated from scatter) --

__global__ void deg_rank_kernel(const int* __restrict__ dst, int* __restrict__ deg,
                                int* __restrict__ rank) {
    int i = blockIdx.x * blockDim.x + threadIdx.x;
    if (i < N_EDGES) rank[i] = atomicAdd(&deg[dst[i]], 1);
}

// CSR scan with chunk_sum folded in: each block sums deg[0 .. bid*256) directly
// (coalesced L2 reads, ~19MB total across 196 blocks), then per-chunk scan.

__global__ void scatter_scan(const int* __restrict__ deg,
                             int* __restrict__ row_ptr, float* __restrict__ deg_inv) {
    __shared__ int s[256];
    __shared__ int base_s;
    const int tid = threadIdx.x;
    const int bid = blockIdx.x;
    int sum = 0;
    for (int j = tid; j < bid * 256; j += 256) sum += deg[j];
    s[tid] = sum;
    __syncthreads();
    for (int off = 128; off > 0; off >>= 1) {
        if (tid < off) s[tid] += s[tid + off];
        __syncthreads();
    }
    if (tid == 0) base_s = s[0];
    __syncthreads();
    int i = bid * 256 + tid;
    int v = (i < N_NODES) ? deg[i] : 0;
    s[tid] = v;
    __syncthreads();
    for (int off = 1; off < 256; off <<= 1) {
        int t = (tid >= off) ? s[tid - off] : 0;
        __syncthreads();
        s[tid] += t;
        __syncthreads();
    }
    if (i < N_NODES) {
        int rp = base_s + s[tid] - v;   // exclusive scan value
        row_ptr[i] = rp;
        deg_inv[i] = 1.0f / fmaxf((float)v, 1.0f);
        if (i == N_NODES - 1) row_ptr[N_NODES] = N_EDGES;
    }
}

// Atomic-free scatter: position = row_ptr[dst] + rank.
__global__ void fill_csr(const int* __restrict__ src, const int* __restrict__ dst,
                         const int* __restrict__ rank, const int* __restrict__ row_ptr,
                         int* __restrict__ csr_src) {
    int e = blockIdx.x * blockDim.x + threadIdx.x;
    if (e < N_EDGES) {
        csr_src[row_ptr[dst[e]] + rank[e]] = src[e];
    }
}

// ---------------- mean aggregation (full-TLP standalone kernels, R1-exact) ---

__device__ __forceinline__ void add_row(const float4& v, float2 (&acc)[4]) {
    const __half2* hp = (const __half2*)&v;
    #pragma unroll
    for (int j = 0; j < 4; ++j) {
        float2 f = __half22float2(hp[j]);
        acc[j].x += f.x;
        acc[j].y += f.y;
    }
}

template<bool ACCUM_F32>
__device__ __forceinline__ void gather_core(const __half2* __restrict__ feat,
                                            const int* __restrict__ row_ptr,
                                            const int* __restrict__ csr_src,
                                            const float* __restrict__ deg_inv,
                                            __half2* __restrict__ outh,
                                            float* __restrict__ outf) {
    const float4* feat4 = (const float4*)feat;
    const int lane = threadIdx.x & 63;
    const int g = lane >> 4;          // edge slot 0..3
    const int s = lane & 15;          // 16B chunk within row
    const int n = blockIdx.x * 4 + (threadIdx.x >> 6);
    const int beg = row_ptr[n];
    const int end = row_ptr[n + 1];
    float2 acc[4] = {};

    int idx = (beg + lane < end) ? csr_src[beg + lane] : 0;
    int base = beg;
    while (base < end) {
        int cnt = end - base;
        if (cnt > 64) cnt = 64;
        const int nbase = base + 64;
        int nidx = (nbase + lane < end) ? csr_src[nbase + lane] : 0;

        int it = 0;
        for (; it + 16 <= cnt; it += 16) {  // 4 independent 4-row loads in flight
            int s0 = __shfl(idx, it + g);
            int s1 = __shfl(idx, it + 4 + g);
            int s2 = __shfl(idx, it + 8 + g);
            int s3 = __shfl(idx, it + 12 + g);
            float4 v0 = feat4[(size_t)s0 * 16 + s];
            float4 v1 = feat4[(size_t)s1 * 16 + s];
            float4 v2 = feat4[(size_t)s2 * 16 + s];
            float4 v3 = feat4[(size_t)s3 * 16 + s];
            add_row(v0, acc);
            add_row(v1, acc);
            add_row(v2, acc);
            add_row(v3, acc);
        }
        for (; it + 4 <= cnt; it += 4) {
            int s0 = __shfl(idx, it + g);
            float4 v0 = feat4[(size_t)s0 * 16 + s];
            add_row(v0, acc);
        }
        if (it < cnt) {                   // masked tail (1..3 edges)
            int s0 = __shfl(idx, it + g);
            if (g < cnt - it) {
                float4 v0 = feat4[(size_t)s0 * 16 + s];
                add_row(v0, acc);
            }
        }
        idx = nidx;
        base = nbase;
    }

    #pragma unroll
    for (int j = 0; j < 4; ++j) {
        acc[j].x += __shfl_xor(acc[j].x, 16);
        acc[j].y += __shfl_xor(acc[j].y, 16);
        acc[j].x += __shfl_xor(acc[j].x, 32);
        acc[j].y += __shfl_xor(acc[j].y, 32);
    }
    if (g == 0) {
        float di = deg_inv[n];
        if (ACCUM_F32) {
            float4* orow = (float4*)(outf + (size_t)n * 128);
            float4 o0 = orow[s * 2];
            float4 o1 = orow[s * 2 + 1];
            o0.x += acc[0].x * di; o0.y += acc[0].y * di;
            o0.z += acc[1].x * di; o0.w += acc[1].y * di;
            o1.x += acc[2].x * di; o1.y += acc[2].y * di;
            o1.z += acc[3].x * di; o1.w += acc[3].y * di;
            orow[s * 2] = o0;
            orow[s * 2 + 1] = o1;
        } else {
            float4 o;
            __half2* op = (__half2*)&o;
            op[0] = __float22half2_rn(make_float2(acc[0].x * di, acc[0].y * di));
            op[1] = __float22half2_rn(make_float2(acc[1].x * di, acc[1].y * di));
            op[2] = __float22half2_rn(make_float2(acc[2].x * di, acc[2].y * di));
            op[3] = __float22half2_rn(make_float2(acc[3].x * di, acc[3].y * di));
            ((float4*)(outh + (size_t)n * 64))[s] = o;
        }
    }
}

__global__ __launch_bounds__(256)
void gather_mean_h(const __half2* __restrict__ feat, const int* __restrict__ row_ptr,
                   const int* __restrict__ csr_src, const float* __restrict__ deg_inv,
                   __half2* __restrict__ outv) {
    gather_core<false>(feat, row_ptr, csr_src, deg_inv, outv, nullptr);
}

__global__ __launch_bounds__(256)
void gather_mean_add_f32(const __half2* __restrict__ feat, const int* __restrict__ row_ptr,
                         const int* __restrict__ csr_src, const float* __restrict__ deg_inv,
                         float* __restrict__ out) {
    gather_core<true>(feat, row_ptr, csr_src, deg_inv, nullptr, out);
}

// ---------------- fused MFMA GEMM v3: R1 dataflow, 1 barrier/tile ------------
// Identical math/fragments to R1's gemm_fused (best measured). Change: ldsH is
// double-buffered and each barrier-to-barrier region contains consume(t) from
// buf + produce(t+1) into buf^1 -> ONE __syncthreads per tile (vs 2), and each
// vmcnt(0)-drain at the barrier is amortized over 64 wave-MFMAs of independent
// work instead of ~32 with empty regions.
// Safety: produce at iter i+1 writes buf only after the i+1 barrier, which is
// after all consume(t_i) reads of buf completed -> no WAR hazard.
// mfma_f32_16x16x32_f16 layouts (verified R4..R11 + rounds 1-6 numerics):
//   A frag: lane holds A[m = lane&15][k = kc*32 + (lane>>4)*8 + j]
//   B frag: lane holds W[n = lane&15][k]  (W row-major [J,K])
//   C/D:    col = lane&15 (n), row = (lane>>4)*4 + reg

#define HPAD 264

__global__ __launch_bounds__(256, 1)
void gemm_fused3(const __half* __restrict__ Aa, const __half* __restrict__ Ba,
                 const __half* __restrict__ Ab, const __half* __restrict__ Bb,
                 const float* __restrict__ bias1,
                 const __half* __restrict__ B20, const __half* __restrict__ B21,
                 const float* __restrict__ bias2,
                 __half* __restrict__ P, float* __restrict__ out) {
    __shared__ __half hlds[2][16][HPAD];
    const int lane = threadIdx.x & 63;
    const int wave = threadIdx.x >> 6;
    const int quad = lane >> 4;
    const int l16 = lane & 15;
    const int koff = quad * 8;

    // Layer-1 B fragments: bf1[pass][kc][nt]  (wave owns h cols wave*64..+64)
    f16x8 bf1[2][4][4];
    #pragma unroll
    for (int p = 0; p < 2; ++p) {
        const __half* __restrict__ B = p ? Bb : Ba;
        #pragma unroll
        for (int kc = 0; kc < 4; ++kc)
            #pragma unroll
            for (int nt = 0; nt < 4; ++nt)
                bf1[p][kc][nt] = *(const f16x8*)(
                    B + (size_t)(wave * 64 + nt * 16 + l16) * D_IN + kc * 32 + koff);
    }
    float bv1[4];
    #pragma unroll
    for (int nt = 0; nt < 4; ++nt) bv1[nt] = bias1[wave * 64 + nt * 16 + l16];

    // Layer-2 B fragments: bf20/bf21[kc][nt]  (wave owns P/OUT cols wave*32..+32)
    f16x8 bf20[8][2], bf21[8][2];
    #pragma unroll
    for (int kc = 0; kc < 8; ++kc)
        #pragma unroll
        for (int nt = 0; nt < 2; ++nt) {
            size_t brow = (size_t)(wave * 32 + nt * 16 + l16) * D_HID + kc * 32 + koff;
            bf20[kc][nt] = *(const f16x8*)(B20 + brow);
            bf21[kc][nt] = *(const f16x8*)(B21 + brow);
        }
    float bv2[2];
    #pragma unroll
    for (int nt = 0; nt < 2; ++nt) bv2[nt] = bias2[wave * 32 + nt * 16 + l16];

    const int g = gridDim.x;

    auto loadA = [&](int t, f16x8 (&a)[2][4]) {
        const size_t arow = (size_t)(t * 16 + l16) * D_IN + koff;
        #pragma unroll
        for (int kc = 0; kc < 4; ++kc) {
            a[0][kc] = *(const f16x8*)(Aa + arow + kc * 32);
            a[1][kc] = *(const f16x8*)(Ab + arow + kc * 32);
        }
    };

    auto produce = [&](const f16x8 (&a)[2][4], int buf) {
        f32x4 acc1[4] = {};
        #pragma unroll
        for (int p = 0; p < 2; ++p)
            #pragma unroll
            for (int kc = 0; kc < 4; ++kc)
                #pragma unroll
                for (int nt = 0; nt < 4; ++nt)
                    acc1[nt] = __builtin_amdgcn_mfma_f32_16x16x32_f16(
                        a[p][kc], bf1[p][kc][nt], acc1[nt], 0, 0, 0);
        #pragma unroll
        for (int nt = 0; nt < 4; ++nt) {
            int col = wave * 64 + nt * 16 + l16;
            #pragma unroll
            for (int r = 0; r < 4; ++r)
                hlds[buf][quad * 4 + r][col] =
                    __float2half(fmaxf(acc1[nt][r] + bv1[nt], 0.f));
        }
    };

    auto consume = [&](int tile, int buf) {
        f32x4 acc20[2] = {};
        f32x4 acc21[2] = {};
        #pragma unroll
        for (int kc = 0; kc < 8; ++kc) {
            f16x8 a2 = *(const f16x8*)&hlds[buf][l16][kc * 32 + koff];
            #pragma unroll
            for (int nt = 0; nt < 2; ++nt) {
                acc20[nt] = __builtin_amdgcn_mfma_f32_16x16x32_f16(
                    a2, bf20[kc][nt], acc20[nt], 0, 0, 0);
                acc21[nt] = __builtin_amdgcn_mfma_f32_16x16x32_f16(
                    a2, bf21[kc][nt], acc21[nt], 0, 0, 0);
            }
        }
        #pragma unroll
        for (int nt = 0; nt < 2; ++nt) {
            int col = wave * 32 + nt * 16 + l16;
            #pragma unroll
            for (int r = 0; r < 4; ++r) {
                int row = tile * 16 + quad * 4 + r;
                P[(size_t)row * D_OUT + col] = __float2half(acc20[nt][r]);
                out[(size_t)row * D_OUT + col] = acc21[nt][r] + bv2[nt];
            }
        }
    };

    // pipeline: loadA(t+2g) | produce(t+g) | consume(t); 1 barrier per tile
    f16x8 A0[2][4], A1[2][4];
    int t = blockIdx.x;          // g=512 <= NTILES so every block has work
    int buf = 0;
    loadA(t, A0);
    produce(A0, 0);              // h(t) -> buf0 (visible after first barrier)
    if (t + g < NTILES) loadA(t + g, A1);
    while (true) {
        __syncthreads();                     // h(t) ready in buf
        consume(t, buf);
        if (t + g >= NTILES) break;
        produce(A1, buf ^ 1);                // h(t+g) -> other buffer
        if (t + 2 * g < NTILES) loadA(t + 2 * g, A0);
        t += g; buf ^= 1;

        __syncthreads();
        consume(t, buf);
        if (t + g >= NTILES) break;
        produce(A0, buf ^ 1);
        if (t + 2 * g < NTILES) loadA(t + 2 * g, A1);
        t += g; buf ^= 1;
    }
}

extern "C" void kernel_launch(void* const* d_in, const int* in_sizes, int n_in,
                              void* d_out, int out_size, void* d_ws, size_t ws_size,
                              hipStream_t stream) {
    const float* x   = (const float*)d_in[0];
    const float* Wl1 = (const float*)d_in[1];
    const float* bl1 = (const float*)d_in[2];
    const float* Wr1 = (const float*)d_in[3];
    const float* Wl2 = (const float*)d_in[4];
    const float* bl2 = (const float*)d_in[5];
    const float* Wr2 = (const float*)d_in[6];
    const int*   ei  = (const int*)d_in[7];
    const int* src = ei;              // edge_index[0]
    const int* dst = ei + N_EDGES;    // edge_index[1]
    float* out = (float*)d_out;

    // Workspace layout, 256B-aligned slabs
    char* w = (char*)d_ws;
    auto alloc = [&](size_t bytes) {
        char* r = w;
        w += (bytes + 255) & ~(size_t)255;
        return r;
    };
    int*     deg       = (int*)alloc((size_t)N_NODES * 4);
    int*     row_ptr   = (int*)alloc((size_t)(N_NODES + 1) * 4);
    int*     rank      = (int*)alloc((size_t)N_EDGES * 4);
    int*     csr_src   = (int*)alloc((size_t)N_EDGES * 4);
    float*   deg_inv   = (float*)alloc((size_t)N_NODES * 4);
    __half2* xb        = (__half2*)alloc((size_t)N_NODES * 64 * 4);   // x fp16
    __half2* mean1     = (__half2*)alloc((size_t)N_NODES * 64 * 4);   // mean(x) fp16
    __half2* pb        = (__half2*)alloc((size_t)N_NODES * 64 * 4);   // h@Wl2^T fp16
    __half*  wl1h      = (__half*)alloc(4 * 32768 * 2);
    __half*  wr1h = wl1h + 32768;
    __half*  wl2h = wr1h + 32768;
    __half*  wr2h = wl2h + 32768;

    // Fused prep: x->fp16, weights->fp16, deg=0 (one dispatch)
    prep_kernel<<<3337, 256, 0, stream>>>(x, (__half*)xb, Wl1, Wr1, Wl2, Wr2,
        wl1h, wr1h, wl2h, wr2h, deg);

    // CSR build: rank-split (atomics decoupled from scatter stores)
    deg_rank_kernel<<<(N_EDGES + 255) / 256, 256, 0, stream>>>(dst, deg, rank);
    scatter_scan<<<NCHUNK, 256, 0, stream>>>(deg, row_ptr, deg_inv);
    fill_csr<<<(N_EDGES + 255) / 256, 256, 0, stream>>>(src, dst, rank, row_ptr, csr_src);

    // Layer 1 aggregation (full TLP: 12500 blocks, wave per node)
    gather_mean_h<<<12500, 256, 0, stream>>>(xb, row_ptr, csr_src, deg_inv, mean1);

    // Fused GEMMs v3: h in LDS (dbuf, 1 barrier/tile); P = h@Wl2^T; out = h@Wr2^T + b2
    gemm_fused3<<<GEMM_GRID, 256, 0, stream>>>(
        (const __half*)mean1, wl1h, (const __half*)xb, wr1h, bl1,
        wl2h, wr2h, bl2, (__half*)pb, out);

    // out += mean(P)
    gather_mean_add_f32<<<12500, 256, 0, stream>>>(pb, row_ptr, csr_src, deg_inv, out);
}

// Round 8
// 236.008 us; speedup vs baseline: 1.1106x; 1.1106x over previous
//
#include <hip/hip_runtime.h>
#include <hip/hip_fp16.h>

#define N_NODES 50000
#define N_EDGES 800000
#define D_IN 128
#define D_HID 256
#define D_OUT 128
#define NCHUNK 196   // ceil(N_NODES / 256)
#define GEMM_GRID 512
#define DEGS 32      // deg spread stride: 1 node per 128B line (atomic contention fix)

typedef _Float16 f16x8 __attribute__((ext_vector_type(8)));
typedef float f32x4 __attribute__((ext_vector_type(4)));

// ---------------- fused prep: zero_deg + cvt x + cvt weights ------------------
// 16B/lane vectorized: blocks [0,3125): xb; [3125,3141): 4 weight mats;
// [3141,3337): zero deg (spread: only slots node*DEGS are used/zeroed).

__device__ __forceinline__ void cvt8(const float* __restrict__ src,
                                     __half* __restrict__ dstp, int i) {
    const float4* s4 = (const float4*)src;
    float4 a = s4[i * 2];
    float4 b = s4[i * 2 + 1];
    float4 o;
    __half2* op = (__half2*)&o;
    op[0] = __float22half2_rn(make_float2(a.x, a.y));
    op[1] = __float22half2_rn(make_float2(a.z, a.w));
    op[2] = __float22half2_rn(make_float2(b.x, b.y));
    op[3] = __float22half2_rn(make_float2(b.z, b.w));
    ((float4*)dstp)[i] = o;
}

__global__ __launch_bounds__(256)
void prep_kernel(const float* __restrict__ x, __half* __restrict__ xb,
                 const float* __restrict__ Wl1, const float* __restrict__ Wr1,
                 const float* __restrict__ Wl2, const float* __restrict__ Wr2,
                 __half* __restrict__ wl1h, __half* __restrict__ wr1h,
                 __half* __restrict__ wl2h, __half* __restrict__ wr2h,
                 int* __restrict__ deg) {
    int b = blockIdx.x;
    if (b < 3125) {
        int i = b * 256 + threadIdx.x;            // 800000 threads x 8 floats
        cvt8(x, xb, i);
    } else if (b < 3141) {
        int i = (b - 3125) * 256 + threadIdx.x;   // 4096 threads x 8 floats/mat
        cvt8(Wl1, wl1h, i);
        cvt8(Wr1, wr1h, i);
        cvt8(Wl2, wl2h, i);
        cvt8(Wr2, wr2h, i);
    } else {
        int i = (b - 3141) * 256 + threadIdx.x;
        if (i < N_NODES) deg[i * DEGS] = 0;
    }
}

// ---------------- CSR build: rank-split (atomic pass separated from scatter) --
// deg spread onto 128B lines: ~16 same-line RMWs per line (one node's edges)
// instead of ~256 (4 packed nodes x 16 edges x 4/line) -> memory-side atomic
// unit processes lines in parallel instead of queueing on 3125 hot lines.

__global__ void deg_rank_kernel(const int* __restrict__ dst, int* __restrict__ deg,
                                int* __restrict__ rank) {
    int i = blockIdx.x * blockDim.x + threadIdx.x;
    if (i < N_EDGES) rank[i] = atomicAdd(&deg[dst[i] * DEGS], 1);
}

__global__ void chunk_sum(const int* __restrict__ deg, int* __restrict__ partial) {
    __shared__ int s[256];
    int i = blockIdx.x * 256 + threadIdx.x;
    s[threadIdx.x] = (i < N_NODES) ? deg[i * DEGS] : 0;
    __syncthreads();
    for (int off = 128; off > 0; off >>= 1) {
        if (threadIdx.x < off) s[threadIdx.x] += s[threadIdx.x + off];
        __syncthreads();
    }
    if (threadIdx.x == 0) partial[blockIdx.x] = s[0];
}

// Per-chunk scan with integrated cross-chunk base (chunk_scan merged in).
__global__ void scatter_scan(const int* __restrict__ deg, const int* __restrict__ partial,
                             int* __restrict__ row_ptr, float* __restrict__ deg_inv) {
    __shared__ int s[256];
    __shared__ int base_s;
    const int tid = threadIdx.x;
    const int bid = blockIdx.x;
    // base = sum partial[0..bid)   (NCHUNK = 196 < 256)
    s[tid] = (tid < bid) ? partial[tid] : 0;
    __syncthreads();
    for (int off = 128; off > 0; off >>= 1) {
        if (tid < off) s[tid] += s[tid + off];
        __syncthreads();
    }
    if (tid == 0) base_s = s[0];
    __syncthreads();
    // per-chunk inclusive scan (Hillis-Steele)
    int i = bid * 256 + tid;
    int v = (i < N_NODES) ? deg[i * DEGS] : 0;
    s[tid] = v;
    __syncthreads();
    for (int off = 1; off < 256; off <<= 1) {
        int t = (tid >= off) ? s[tid - off] : 0;
        __syncthreads();
        s[tid] += t;
        __syncthreads();
    }
    if (i < N_NODES) {
        int rp = base_s + s[tid] - v;   // exclusive scan value
        row_ptr[i] = rp;
        deg_inv[i] = 1.0f / fmaxf((float)v, 1.0f);
        if (i == N_NODES - 1) row_ptr[N_NODES] = N_EDGES;
    }
}

// Atomic-free scatter: position = row_ptr[dst] + rank. Fire-and-forget stores.
__global__ void fill_csr(const int* __restrict__ src, const int* __restrict__ dst,
                         const int* __restrict__ rank, const int* __restrict__ row_ptr,
                         int* __restrict__ csr_src) {
    int e = blockIdx.x * blockDim.x + threadIdx.x;
    if (e < N_EDGES) {
        csr_src[row_ptr[dst[e]] + rank[e]] = src[e];
    }
}

// ---------------- mean aggregation (R1-exact) --------------------------------
// coalesced index preload (1 lane-parallel csr_src load per 64 edges,
// distributed via __shfl); packed float2 accumulation.

__device__ __forceinline__ void add_row(const float4& v, float2 (&acc)[4]) {
    const __half2* hp = (const __half2*)&v;
    #pragma unroll
    for (int j = 0; j < 4; ++j) {
        float2 f = __half22float2(hp[j]);
        acc[j].x += f.x;
        acc[j].y += f.y;
    }
}

template<bool ACCUM_F32>
__device__ __forceinline__ void gather_core(const __half2* __restrict__ feat,
                                            const int* __restrict__ row_ptr,
                                            const int* __restrict__ csr_src,
                                            const float* __restrict__ deg_inv,
                                            __half2* __restrict__ outh,
                                            float* __restrict__ outf) {
    const float4* feat4 = (const float4*)feat;
    const int lane = threadIdx.x & 63;
    const int g = lane >> 4;          // edge slot 0..3
    const int s = lane & 15;          // 16B chunk within row
    const int n = blockIdx.x * 4 + (threadIdx.x >> 6);
    const int beg = row_ptr[n];
    const int end = row_ptr[n + 1];
    float2 acc[4] = {};

    int idx = (beg + lane < end) ? csr_src[beg + lane] : 0;
    int base = beg;
    while (base < end) {
        int cnt = end - base;
        if (cnt > 64) cnt = 64;
        const int nbase = base + 64;
        int nidx = (nbase + lane < end) ? csr_src[nbase + lane] : 0;

        int it = 0;
        for (; it + 16 <= cnt; it += 16) {  // 4 independent 4-row loads in flight
            int s0 = __shfl(idx, it + g);
            int s1 = __shfl(idx, it + 4 + g);
            int s2 = __shfl(idx, it + 8 + g);
            int s3 = __shfl(idx, it + 12 + g);
            float4 v0 = feat4[(size_t)s0 * 16 + s];
            float4 v1 = feat4[(size_t)s1 * 16 + s];
            float4 v2 = feat4[(size_t)s2 * 16 + s];
            float4 v3 = feat4[(size_t)s3 * 16 + s];
            add_row(v0, acc);
            add_row(v1, acc);
            add_row(v2, acc);
            add_row(v3, acc);
        }
        for (; it + 4 <= cnt; it += 4) {
            int s0 = __shfl(idx, it + g);
            float4 v0 = feat4[(size_t)s0 * 16 + s];
            add_row(v0, acc);
        }
        if (it < cnt) {                   // masked tail (1..3 edges)
            int s0 = __shfl(idx, it + g);
            if (g < cnt - it) {
                float4 v0 = feat4[(size_t)s0 * 16 + s];
                add_row(v0, acc);
            }
        }
        idx = nidx;
        base = nbase;
    }

    #pragma unroll
    for (int j = 0; j < 4; ++j) {
        acc[j].x += __shfl_xor(acc[j].x, 16);
        acc[j].y += __shfl_xor(acc[j].y, 16);
        acc[j].x += __shfl_xor(acc[j].x, 32);
        acc[j].y += __shfl_xor(acc[j].y, 32);
    }
    if (g == 0) {
        float di = deg_inv[n];
        if (ACCUM_F32) {
            float4* orow = (float4*)(outf + (size_t)n * 128);
            float4 o0 = orow[s * 2];
            float4 o1 = orow[s * 2 + 1];
            o0.x += acc[0].x * di; o0.y += acc[0].y * di;
            o0.z += acc[1].x * di; o0.w += acc[1].y * di;
            o1.x += acc[2].x * di; o1.y += acc[2].y * di;
            o1.z += acc[3].x * di; o1.w += acc[3].y * di;
            orow[s * 2] = o0;
            orow[s * 2 + 1] = o1;
        } else {
            float4 o;
            __half2* op = (__half2*)&o;
            op[0] = __float22half2_rn(make_float2(acc[0].x * di, acc[0].y * di));
            op[1] = __float22half2_rn(make_float2(acc[1].x * di, acc[1].y * di));
            op[2] = __float22half2_rn(make_float2(acc[2].x * di, acc[2].y * di));
            op[3] = __float22half2_rn(make_float2(acc[3].x * di, acc[3].y * di));
            ((float4*)(outh + (size_t)n * 64))[s] = o;
        }
    }
}

__global__ __launch_bounds__(256)
void gather_mean_h(const __half2* __restrict__ feat, const int* __restrict__ row_ptr,
                   const int* __restrict__ csr_src, const float* __restrict__ deg_inv,
                   __half2* __restrict__ outv) {
    gather_core<false>(feat, row_ptr, csr_src, deg_inv, outv, nullptr);
}

__global__ __launch_bounds__(256)
void gather_mean_add_f32(const __half2* __restrict__ feat, const int* __restrict__ row_ptr,
                         const int* __restrict__ csr_src, const float* __restrict__ deg_inv,
                         float* __restrict__ out) {
    gather_core<true>(feat, row_ptr, csr_src, deg_inv, nullptr, out);
}

// ---------------- fused MFMA GEMM (R1-exact, best measured) ------------------
// mfma_f32_16x16x32_f16 layouts (verified R4..R11):
//   A frag: lane holds A[m = lane&15][k = kc*32 + (lane>>4)*8 + j]
//   B frag: lane holds W[n = lane&15][k]  (W row-major [J,K])
//   C/D:    col = lane&15 (n), row = (lane>>4)*4 + reg
// Per 16-row tile: 4 waves compute h(16x256) = relu(mean1@Wl1^T + xb@Wr1^T + b1),
// stage fp16 into padded LDS [16][264] (double-buffered), barrier, then each
// wave computes its 32-col slices of P = h@Wl2^T and OUT = h@Wr2^T + b2.

#define HPAD 264

__global__ __launch_bounds__(256, 1)
void gemm_fused(const __half* __restrict__ Aa, const __half* __restrict__ Ba,
                const __half* __restrict__ Ab, const __half* __restrict__ Bb,
                const float* __restrict__ bias1,
                const __half* __restrict__ B20, const __half* __restrict__ B21,
                const float* __restrict__ bias2,
                __half* __restrict__ P, float* __restrict__ out) {
    __shared__ __half hlds[2][16][HPAD];
    const int lane = threadIdx.x & 63;
    const int wave = threadIdx.x >> 6;
    const int quad = lane >> 4;
    const int l16 = lane & 15;
    const int koff = quad * 8;

    // Layer-1 B fragments: bf1[pass][kc][nt]  (wave owns h cols wave*64..+64)
    f16x8 bf1[2][4][4];
    #pragma unroll
    for (int p = 0; p < 2; ++p) {
        const __half* __restrict__ B = p ? Bb : Ba;
        #pragma unroll
        for (int kc = 0; kc < 4; ++kc)
            #pragma unroll
            for (int nt = 0; nt < 4; ++nt)
                bf1[p][kc][nt] = *(const f16x8*)(
                    B + (size_t)(wave * 64 + nt * 16 + l16) * D_IN + kc * 32 + koff);
    }
    float bv1[4];
    #pragma unroll
    for (int nt = 0; nt < 4; ++nt) bv1[nt] = bias1[wave * 64 + nt * 16 + l16];

    // Layer-2 B fragments: bf20/bf21[kc][nt]  (wave owns P/OUT cols wave*32..+32)
    f16x8 bf20[8][2], bf21[8][2];
    #pragma unroll
    for (int kc = 0; kc < 8; ++kc)
        #pragma unroll
        for (int nt = 0; nt < 2; ++nt) {
            size_t brow = (size_t)(wave * 32 + nt * 16 + l16) * D_HID + kc * 32 + koff;
            bf20[kc][nt] = *(const f16x8*)(B20 + brow);
            bf21[kc][nt] = *(const f16x8*)(B21 + brow);
        }
    float bv2[2];
    #pragma unroll
    for (int nt = 0; nt < 2; ++nt) bv2[nt] = bias2[wave * 32 + nt * 16 + l16];

    const int NT = N_NODES / 16;            // 3125 exact
    const int g = gridDim.x;

    auto loadA = [&](int t, f16x8 (&a)[2][4]) {
        const size_t arow = (size_t)(t * 16 + l16) * D_IN + koff;
        #pragma unroll
        for (int kc = 0; kc < 4; ++kc) {
            a[0][kc] = *(const f16x8*)(Aa + arow + kc * 32);
            a[1][kc] = *(const f16x8*)(Ab + arow + kc * 32);
        }
    };

    auto step = [&](int tile, const f16x8 (&a)[2][4], int buf) {
        // ---- layer 1 ----
        f32x4 acc1[4] = {};
        #pragma unroll
        for (int p = 0; p < 2; ++p)
            #pragma unroll
            for (int kc = 0; kc < 4; ++kc)
                #pragma unroll
                for (int nt = 0; nt < 4; ++nt)
                    acc1[nt] = __builtin_amdgcn_mfma_f32_16x16x32_f16(
                        a[p][kc], bf1[p][kc][nt], acc1[nt], 0, 0, 0);
        // stage h tile (fp16, relu+bias) into LDS
        #pragma unroll
        for (int nt = 0; nt < 4; ++nt) {
            int col = wave * 64 + nt * 16 + l16;
            #pragma unroll
            for (int r = 0; r < 4; ++r)
                hlds[buf][quad * 4 + r][col] =
                    __float2half(fmaxf(acc1[nt][r] + bv1[nt], 0.f));
        }
        __syncthreads();
        // ---- layer 2 (A from LDS) ----
        f32x4 acc20[2] = {};
        f32x4 acc21[2] = {};
        #pragma unroll
        for (int kc = 0; kc < 8; ++kc) {
            f16x8 a2 = *(const f16x8*)&hlds[buf][l16][kc * 32 + koff];
            #pragma unroll
            for (int nt = 0; nt < 2; ++nt) {
                acc20[nt] = __builtin_amdgcn_mfma_f32_16x16x32_f16(
                    a2, bf20[kc][nt], acc20[nt], 0, 0, 0);
                acc21[nt] = __builtin_amdgcn_mfma_f32_16x16x32_f16(
                    a2, bf21[kc][nt], acc21[nt], 0, 0, 0);
            }
        }
        #pragma unroll
        for (int nt = 0; nt < 2; ++nt) {
            int col = wave * 32 + nt * 16 + l16;
            #pragma unroll
            for (int r = 0; r < 4; ++r) {
                int row = tile * 16 + quad * 4 + r;
                P[(size_t)row * D_OUT + col] = __float2half(acc20[nt][r]);
                out[(size_t)row * D_OUT + col] = acc21[nt][r] + bv2[nt];
            }
        }
    };

    f16x8 A0[2][4], A1[2][4];
    int tile = blockIdx.x;
    int buf = 0;
    loadA(tile, A0);
    while (true) {
        if (tile + g < NT) loadA(tile + g, A1);
        step(tile, A0, buf);
        buf ^= 1;
        tile += g;
        if (tile >= NT) break;
        if (tile + g < NT) loadA(tile + g, A0);
        step(tile, A1, buf);
        buf ^= 1;
        tile += g;
        if (tile >= NT) break;
    }
}

extern "C" void kernel_launch(void* const* d_in, const int* in_sizes, int n_in,
                              void* d_out, int out_size, void* d_ws, size_t ws_size,
                              hipStream_t stream) {
    const float* x   = (const float*)d_in[0];
    const float* Wl1 = (const float*)d_in[1];
    const float* bl1 = (const float*)d_in[2];
    const float* Wr1 = (const float*)d_in[3];
    const float* Wl2 = (const float*)d_in[4];
    const float* bl2 = (const float*)d_in[5];
    const float* Wr2 = (const float*)d_in[6];
    const int*   ei  = (const int*)d_in[7];
    const int* src = ei;              // edge_index[0]
    const int* dst = ei + N_EDGES;    // edge_index[1]
    float* out = (float*)d_out;

    // Workspace layout, 256B-aligned slabs (~52 MB)
    char* w = (char*)d_ws;
    auto alloc = [&](size_t bytes) {
        char* r = w;
        w += (bytes + 255) & ~(size_t)255;
        return r;
    };
    int*     deg       = (int*)alloc((size_t)N_NODES * DEGS * 4);  // 1 node / 128B line
    int*     row_ptr   = (int*)alloc((size_t)(N_NODES + 1) * 4);
    int*     rank      = (int*)alloc((size_t)N_EDGES * 4);
    int*     partial   = (int*)alloc(NCHUNK * 4);
    int*     csr_src   = (int*)alloc((size_t)N_EDGES * 4);
    float*   deg_inv   = (float*)alloc((size_t)N_NODES * 4);
    __half2* xb        = (__half2*)alloc((size_t)N_NODES * 64 * 4);   // x fp16
    __half2* mean1     = (__half2*)alloc((size_t)N_NODES * 64 * 4);   // mean(x) fp16
    __half2* pb        = (__half2*)alloc((size_t)N_NODES * 64 * 4);   // h@Wl2^T fp16
    __half*  wl1h      = (__half*)alloc(4 * 32768 * 2);
    __half*  wr1h = wl1h + 32768;
    __half*  wl2h = wr1h + 32768;
    __half*  wr2h = wl2h + 32768;

    // Fused prep: x->fp16, weights->fp16, deg=0 (one dispatch)
    prep_kernel<<<3337, 256, 0, stream>>>(x, (__half*)xb, Wl1, Wr1, Wl2, Wr2,
        wl1h, wr1h, wl2h, wr2h, deg);

    // CSR build: rank-split (atomics decoupled from scatter stores)
    deg_rank_kernel<<<(N_EDGES + 255) / 256, 256, 0, stream>>>(dst, deg, rank);
    chunk_sum<<<NCHUNK, 256, 0, stream>>>(deg, partial);
    scatter_scan<<<NCHUNK, 256, 0, stream>>>(deg, partial, row_ptr, deg_inv);
    fill_csr<<<(N_EDGES + 255) / 256, 256, 0, stream>>>(src, dst, rank, row_ptr, csr_src);

    // Layer 1 aggregation
    gather_mean_h<<<12500, 256, 0, stream>>>(xb, row_ptr, csr_src, deg_inv, mean1);

    // Fused GEMMs: h in LDS; p = h@Wl2^T; out = h@Wr2^T + bl2
    gemm_fused<<<GEMM_GRID, 256, 0, stream>>>(
        (const __half*)mean1, wl1h, (const __half*)xb, wr1h, bl1,
        wl2h, wr2h, bl2, (__half*)pb, out);

    // out += mean(p)
    gather_mean_add_f32<<<12500, 256, 0, stream>>>(pb, row_ptr, csr_src, deg_inv, out);
}